// Round 8
// baseline (259.497 us; speedup 1.0000x reference)
//
#include <hip/hip_runtime.h>

typedef __attribute__((ext_vector_type(8))) short bf16x8;
typedef __attribute__((ext_vector_type(4))) float f32x4;
typedef unsigned short ushort_t;
typedef unsigned int uint_t;

__device__ __forceinline__ ushort_t f2bf(float f) {
    unsigned int x = __builtin_bit_cast(unsigned int, f);
    x += 0x7fffu + ((x >> 16) & 1u);   // RNE
    return (ushort_t)(x >> 16);
}
// pack two fp32 -> bf16x2 (round-half-up): 2 adds + 1 v_perm
__device__ __forceinline__ uint_t pack2_rn(float a, float b) {
    uint_t au = __builtin_bit_cast(uint_t, a) + 0x8000u;
    uint_t bu = __builtin_bit_cast(uint_t, b) + 0x8000u;
    return __builtin_amdgcn_perm(bu, au, 0x07060302);  // {bu.hi16, au.hi16}
}

#define LOG2E 1.4426950408889634f

// ---------------- workspace layout (ushort elements) ----------------
// Identical footprint to the round-6 PASSING kernel: high-water 11141120 ushorts (22.3 MB).
// Wt: 4 x [256][512] bf16 @ 0 ; Wo^T: [512][256] @ 524288
// Q, Q2, K: [8192][256] ; V^T: [1024][2048]  @ 655360 (+2097152 each)
// O: [8192][256] bf16 @ 9043968
#define WT_OFF   0
#define WOT_OFF  524288
#define QKV_OFF  655360
#define QKV_SZ   2097152
#define QKV_OFF_Z3 (3 * (size_t)QKV_SZ)
#define O_OFF    9043968

// ---------------- weight transpose, LDS-tiled, coalesced both sides ----------------
__global__ __launch_bounds__(256) void transpose_w(
    const float* __restrict__ Wq, const float* __restrict__ Wq2,
    const float* __restrict__ Wk, const float* __restrict__ Wv,
    const float* __restrict__ Wo, ushort_t* __restrict__ ws)
{
    const int z = blockIdx.z;
    const float* in;
    ushort_t* outp;
    int R, C;
    float s = 1.0f;
    if (z < 4) {
        in = (z == 0) ? Wq : (z == 1) ? Wq2 : (z == 2) ? Wk : Wv;
        outp = ws + WT_OFF + (size_t)z * 131072;
        R = 512; C = 256;
        if (z < 2) s = 0.125f * LOG2E;   // fold attn scale + exp2 conversion into Wq/Wq2
    } else {
        in = Wo; outp = ws + WOT_OFF; R = 256; C = 512;
    }
    const int rt = blockIdx.x * 64, ct = blockIdx.y * 64;
    if (rt >= R || ct >= C) return;
    __shared__ float lT[64][65];
    const int tid = threadIdx.x;
    const int ci = tid & 63, ri0 = tid >> 6;
#pragma unroll
    for (int it = 0; it < 16; ++it) {
        const int r = ri0 + it * 4;
        lT[r][ci] = in[(size_t)(rt + r) * C + ct + ci];
    }
    __syncthreads();
#pragma unroll
    for (int it = 0; it < 16; ++it) {
        const int orow = ri0 + it * 4;
        outp[(size_t)(ct + orow) * R + rt + ci] = f2bf(lT[ci][orow] * s);
    }
}

// ---------------- projections: 64x256 tile per block ----------------
// z: 0: Q=x1@Wq ; 1: Q2=x2@Wq2 ; 2: K=ctx@Wk ; 3: V^T=(ctx@Wv)^T
__global__ __launch_bounds__(256) void proj_gemm(
    const float* __restrict__ x1, const float* __restrict__ x2,
    const float* __restrict__ ctx, const ushort_t* __restrict__ Wt,
    ushort_t* __restrict__ QKV)
{
    __shared__ __align__(16) ushort_t lA[64 * 40];
    __shared__ __align__(16) ushort_t lB[256 * 40];
    const int z = blockIdx.y;
    const float* A = (z == 0) ? x1 : (z == 1) ? x2 : ctx;
    const ushort_t* Bt = Wt + (size_t)z * 131072;
    const int tid = threadIdx.x;
    const int wave = tid >> 6, lane = tid & 63;
    const int quad = lane >> 4, l16 = lane & 15;
    const size_t row0 = (size_t)blockIdx.x * 64;
    const int sr = tid >> 2, sc8 = (tid & 3) << 3;

    f32x4 acc[16] = {};
    for (int k0 = 0; k0 < 512; k0 += 32) {
        const float* src = A + (row0 + sr) * 512 + k0 + sc8;
        float4 v0 = *(const float4*)src;
        float4 v1 = *(const float4*)(src + 4);
        uint4 packed;
        packed.x = pack2_rn(v0.x, v0.y);
        packed.y = pack2_rn(v0.z, v0.w);
        packed.z = pack2_rn(v1.x, v1.y);
        packed.w = pack2_rn(v1.z, v1.w);
        *(uint4*)&lA[sr * 40 + sc8] = packed;
#pragma unroll
        for (int rr = 0; rr < 4; ++rr)
            *(uint4*)&lB[(rr * 64 + sr) * 40 + sc8] =
                *(const uint4*)(Bt + (size_t)(rr * 64 + sr) * 512 + k0 + sc8);
        __syncthreads();
        bf16x8 af = *(const bf16x8*)&lA[(wave * 16 + l16) * 40 + quad * 8];
        if (z == 3) {
#pragma unroll
            for (int c = 0; c < 16; ++c) {
                bf16x8 bfr = *(const bf16x8*)&lB[(c * 16 + l16) * 40 + quad * 8];
                acc[c] = __builtin_amdgcn_mfma_f32_16x16x32_bf16(af, bfr, acc[c], 0, 0, 0);
            }
        } else {
#pragma unroll
            for (int c = 0; c < 16; ++c) {
                bf16x8 bfr = *(const bf16x8*)&lB[(c * 16 + l16) * 40 + quad * 8];
                acc[c] = __builtin_amdgcn_mfma_f32_16x16x32_bf16(bfr, af, acc[c], 0, 0, 0);
            }
        }
        __syncthreads();
    }
    if (z == 3) {
        const int b = (int)(row0 >> 11);
        const int tokl = ((int)row0 & 2047) + wave * 16 + quad * 4;
        ushort_t* Vt = QKV + QKV_OFF_Z3;
#pragma unroll
        for (int c = 0; c < 16; ++c) {
            const int col = c * 16 + l16;
            const int h = col >> 6, d = col & 63;
            uint2 w;
            w.x = pack2_rn(acc[c][0], acc[c][1]);
            w.y = pack2_rn(acc[c][2], acc[c][3]);
            *(uint2*)(Vt + ((size_t)((b * 4 + h) * 64 + d)) * 2048 + tokl) = w;
        }
    } else {
        ushort_t* C = QKV + (size_t)z * QKV_SZ;
        const size_t tok = row0 + wave * 16 + l16;
#pragma unroll
        for (int c = 0; c < 16; ++c) {
            uint2 w;
            w.x = pack2_rn(acc[c][0], acc[c][1]);
            w.y = pack2_rn(acc[c][2], acc[c][3]);
            *(uint2*)(C + tok * 256 + c * 16 + quad * 4) = w;
        }
    }
}

// ---------------- output projection: 64x256 tile, C^T orientation ----------------
__global__ __launch_bounds__(256) void out_gemm(
    const ushort_t* __restrict__ Op, const ushort_t* __restrict__ Wot,
    const float* __restrict__ bias, float* __restrict__ out)
{
    __shared__ __align__(16) ushort_t lA[64 * 40];
    __shared__ __align__(16) ushort_t lB[256 * 40];
    const int tid = threadIdx.x;
    const int wave = tid >> 6, lane = tid & 63;
    const int quad = lane >> 4, l16 = lane & 15;
    const size_t row0 = (size_t)blockIdx.x * 64;
    const int col0 = blockIdx.y * 256;
    const int sr = tid >> 2, sc8 = (tid & 3) << 3;

    f32x4 acc[16] = {};
    for (int k0 = 0; k0 < 256; k0 += 32) {
        *(uint4*)&lA[sr * 40 + sc8] = *(const uint4*)(Op + (row0 + sr) * 256 + k0 + sc8);
#pragma unroll
        for (int rr = 0; rr < 4; ++rr)
            *(uint4*)&lB[(rr * 64 + sr) * 40 + sc8] =
                *(const uint4*)(Wot + (size_t)(col0 + rr * 64 + sr) * 256 + k0 + sc8);
        __syncthreads();
        bf16x8 af = *(const bf16x8*)&lA[(wave * 16 + l16) * 40 + quad * 8];
#pragma unroll
        for (int c = 0; c < 16; ++c) {
            bf16x8 bfr = *(const bf16x8*)&lB[(c * 16 + l16) * 40 + quad * 8];
            acc[c] = __builtin_amdgcn_mfma_f32_16x16x32_bf16(bfr, af, acc[c], 0, 0, 0);
        }
        __syncthreads();
    }
    const size_t tok = row0 + wave * 16 + l16;
#pragma unroll
    for (int c = 0; c < 16; ++c) {
        const int col = col0 + c * 16 + quad * 4;
        const float4 bv = *(const float4*)&bias[col];
        float4 o;
        o.x = acc[c][0] + bv.x; o.y = acc[c][1] + bv.y;
        o.z = acc[c][2] + bv.z; o.w = acc[c][3] + bv.w;
        *(float4*)&out[tok * 512 + col] = o;
    }
}

// ---------------- fused dual-softmax flash attention, 40 KB LDS ----------------
// S^T = K·Q^T, static-max (p = exp2(s)), O^T = V^T·P^T.
// K LDS: [ktok][64 d], 16B groups XOR-swizzled by ktok&7. V^T LDS: [d][64 tok], same.
// P LDS: ONE per-wave [16 q][64 k] buffer, 8-short groups XOR-swizzled by q&7,
// reused sequentially for map1 then map2 (same-wave DS ordering makes WAR safe).

#define ATTN_STAGE(MB, BUF) do {                                                        \
    _Pragma("unroll")                                                                   \
    for (int it_ = 0; it_ < 2; ++it_) {                                                 \
        const int cc_ = tid + it_ * 256;                                                \
        const int g_ = (cc_ ^ (cc_ >> 3)) & 7;                                          \
        const ushort_t* kp_ = Kb + (size_t)(tok0 + (MB) + (cc_ >> 3)) * 256 + in0 + g_ * 8; \
        __builtin_amdgcn_global_load_lds(                                               \
            (const __attribute__((address_space(1))) void*)kp_,                         \
            (__attribute__((address_space(3))) void*)&lK[BUF][cc_ * 8], 16, 0, 0);      \
        const ushort_t* vp_ = Vt + (size_t)(bh64 + (cc_ >> 3)) * 2048 + (MB) + g_ * 8;  \
        __builtin_amdgcn_global_load_lds(                                               \
            (const __attribute__((address_space(1))) void*)vp_,                         \
            (__attribute__((address_space(3))) void*)&lV[BUF][cc_ * 8], 16, 0, 0);      \
    }                                                                                   \
} while (0)

#define P_WRITE(ST, LS) do {                                                            \
    _Pragma("unroll")                                                                   \
    for (int c = 0; c < 4; ++c) {                                                       \
        float p0 = __builtin_amdgcn_exp2f(ST[c][0]);                                    \
        float p1 = __builtin_amdgcn_exp2f(ST[c][1]);                                    \
        float p2 = __builtin_amdgcn_exp2f(ST[c][2]);                                    \
        float p3 = __builtin_amdgcn_exp2f(ST[c][3]);                                    \
        LS += (p0 + p1) + (p2 + p3);                                                    \
        uint2 w; w.x = pack2_rn(p0, p1); w.y = pack2_rn(p2, p3);                        \
        *(uint2*)&lPw[l16 * 64 + ((((c * 2 + (quad >> 1)) ^ l7) & 7) << 3) +            \
                      ((quad & 1) << 2)] = w;                                           \
    }                                                                                   \
} while (0)

#define PV_MFMA(OA, PAV, P) do {                                                        \
    _Pragma("unroll")                                                                   \
    for (int c = 0; c < 4; ++c) {                                                       \
        _Pragma("unroll")                                                               \
        for (int ks = 0; ks < 2; ++ks) {                                                \
            bf16x8 vf = *(const bf16x8*)&lV[P][(c * 16 + l16) * 64 +                    \
                                              ((((ks * 4 + quad) ^ l7) & 7) << 3)];     \
            OA[c] = __builtin_amdgcn_mfma_f32_16x16x32_bf16(vf, PAV[ks], OA[c], 0, 0, 0); \
        } }                                                                             \
} while (0)

#define ATTN_ITER(I, P) do {                                                            \
    __syncthreads();                                                                    \
    { const int mn_ = ((I) + 1) * 64; if (mn_ < 2048) ATTN_STAGE(mn_, 1 - (P)); }       \
    f32x4 st1[4] = {}, st2[4] = {};                                                     \
    _Pragma("unroll")                                                                   \
    for (int c = 0; c < 4; ++c) {                                                       \
        _Pragma("unroll")                                                               \
        for (int ks = 0; ks < 2; ++ks) {                                                \
            bf16x8 kf = *(const bf16x8*)&lK[P][(c * 16 + l16) * 64 +                    \
                                              ((((ks * 4 + quad) ^ l7) & 7) << 3)];     \
            st1[c] = __builtin_amdgcn_mfma_f32_16x16x32_bf16(kf, q1f[ks], st1[c], 0, 0, 0); \
            st2[c] = __builtin_amdgcn_mfma_f32_16x16x32_bf16(kf, q2f[ks], st2[c], 0, 0, 0); \
        } }                                                                             \
    P_WRITE(st1, l1);                                                                   \
    bf16x8 pa[2];                                                                       \
    _Pragma("unroll")                                                                   \
    for (int ks = 0; ks < 2; ++ks)                                                      \
        pa[ks] = *(const bf16x8*)&lPw[l16 * 64 + ((((ks * 4 + quad) ^ l7) & 7) << 3)];  \
    PV_MFMA(o1, pa, P);                                                                 \
    P_WRITE(st2, l2);                                                                   \
    _Pragma("unroll")                                                                   \
    for (int ks = 0; ks < 2; ++ks)                                                      \
        pa[ks] = *(const bf16x8*)&lPw[l16 * 64 + ((((ks * 4 + quad) ^ l7) & 7) << 3)];  \
    PV_MFMA(o2, pa, P);                                                                 \
} while (0)

__global__ __launch_bounds__(256, 4) void attn_fused(
    const ushort_t* __restrict__ Qb, const ushort_t* __restrict__ Q2b,
    const ushort_t* __restrict__ Kb, const ushort_t* __restrict__ Vt,
    ushort_t* __restrict__ Ob)
{
    __shared__ __align__(16) ushort_t lK[2][64 * 64];   // 16 KB
    __shared__ __align__(16) ushort_t lV[2][64 * 64];   // 16 KB
    __shared__ __align__(16) ushort_t lP[4][16 * 64];   // 8 KB  -> 40 KB total = 4 blocks/CU

    const int qt = blockIdx.x;
    const int bh = blockIdx.y;
    const int tid = threadIdx.x;
    const int wave = tid >> 6, lane = tid & 63;
    const int quad = lane >> 4, l16 = lane & 15;
    const int l7 = l16 & 7;
    const size_t tok0 = (size_t)(bh >> 2) * 2048;
    const int in0 = (bh & 3) * 64;
    const int bh64 = bh * 64;
    ushort_t* lPw = &lP[wave][0];

    // Q fragments: direct global load (B-operand layout is row-contiguous 16B)
    bf16x8 q1f[2], q2f[2];
    {
        const ushort_t* qr1 = Qb  + (tok0 + qt * 64 + wave * 16 + l16) * 256 + in0;
        const ushort_t* qr2 = Q2b + (tok0 + qt * 64 + wave * 16 + l16) * 256 + in0;
#pragma unroll
        for (int ks = 0; ks < 2; ++ks) {
            q1f[ks] = *(const bf16x8*)(qr1 + ks * 32 + quad * 8);
            q2f[ks] = *(const bf16x8*)(qr2 + ks * 32 + quad * 8);
        }
    }

    ATTN_STAGE(0, 0);

    f32x4 o1[4] = {}, o2[4] = {};
    float l1 = 0.f, l2 = 0.f;

    for (int i = 0; i < 32; i += 2) {
        ATTN_ITER(i, 0);
        ATTN_ITER(i + 1, 1);
    }

    l1 += __shfl_xor(l1, 16, 64); l1 += __shfl_xor(l1, 32, 64);
    l2 += __shfl_xor(l2, 16, 64); l2 += __shfl_xor(l2, 32, 64);
    const float inv1 = 0.3f / l1, inv2 = 0.7f / l2;

    // O^T C-layout: row d = c*16 + quad*4 + r, col q = l16
    ushort_t* orow = Ob + (tok0 + qt * 64 + wave * 16 + l16) * 256 + in0;
#pragma unroll
    for (int c = 0; c < 4; ++c) {
        const float f0 = o1[c][0] * inv1 + o2[c][0] * inv2;
        const float f1 = o1[c][1] * inv1 + o2[c][1] * inv2;
        const float f2 = o1[c][2] * inv1 + o2[c][2] * inv2;
        const float f3 = o1[c][3] * inv1 + o2[c][3] * inv2;
        uint2 w; w.x = pack2_rn(f0, f1); w.y = pack2_rn(f2, f3);
        *(uint2*)(orow + c * 16 + quad * 4) = w;
    }
}

// ---------------- launch ----------------
extern "C" void kernel_launch(void* const* d_in, const int* in_sizes, int n_in,
                              void* d_out, int out_size, void* d_ws, size_t ws_size,
                              hipStream_t stream)
{
    (void)in_sizes; (void)n_in; (void)out_size; (void)ws_size;
    const float* x1  = (const float*)d_in[0];
    const float* x2  = (const float*)d_in[1];
    const float* ctx = (const float*)d_in[2];
    const float* Wq  = (const float*)d_in[3];
    const float* Wq2 = (const float*)d_in[4];
    const float* Wk  = (const float*)d_in[5];
    const float* Wv  = (const float*)d_in[6];
    const float* Wo  = (const float*)d_in[7];
    const float* bo  = (const float*)d_in[8];
    ushort_t* ws  = (ushort_t*)d_ws;
    float* out = (float*)d_out;

    ushort_t* Wt  = ws + WT_OFF;
    ushort_t* Wot = ws + WOT_OFF;
    ushort_t* QKV = ws + QKV_OFF;
    ushort_t* Q   = QKV;
    ushort_t* Q2  = QKV + 1 * (size_t)QKV_SZ;
    ushort_t* Kp  = QKV + 2 * (size_t)QKV_SZ;
    ushort_t* Vt  = QKV + 3 * (size_t)QKV_SZ;
    ushort_t* Op  = ws + O_OFF;

    transpose_w<<<dim3(8, 8, 5), 256, 0, stream>>>(Wq, Wq2, Wk, Wv, Wo, ws);
    proj_gemm  <<<dim3(128, 4), 256, 0, stream>>>(x1, x2, ctx, Wt, QKV);
    attn_fused <<<dim3(32, 16), 256, 0, stream>>>(Q, Q2, Kp, Vt, Op);
    out_gemm   <<<dim3(128, 2), 256, 0, stream>>>(Op, Wot, bo, out);
}

// Round 9
// 202.940 us; speedup vs baseline: 1.2787x; 1.2787x over previous
//
#include <hip/hip_runtime.h>

typedef __attribute__((ext_vector_type(8))) short bf16x8;
typedef __attribute__((ext_vector_type(4))) float f32x4;
typedef unsigned short ushort_t;
typedef unsigned int uint_t;

__device__ __forceinline__ ushort_t f2bf(float f) {
    unsigned int x = __builtin_bit_cast(unsigned int, f);
    x += 0x7fffu + ((x >> 16) & 1u);   // RNE
    return (ushort_t)(x >> 16);
}
// pack two fp32 -> bf16x2 (round-half-up): 2 adds + 1 v_perm
__device__ __forceinline__ uint_t pack2_rn(float a, float b) {
    uint_t au = __builtin_bit_cast(uint_t, a) + 0x8000u;
    uint_t bu = __builtin_bit_cast(uint_t, b) + 0x8000u;
    return __builtin_amdgcn_perm(bu, au, 0x07060302);  // {bu.hi16, au.hi16}
}

#define LOG2E 1.4426950408889634f

// ---------------- workspace layout (ushort elements) ----------------
// High-water 11141120 ushorts (22.3 MB) — same as round-6 passing kernel.
#define WT_OFF   0
#define WOT_OFF  524288
#define QKV_OFF  655360
#define QKV_SZ   2097152
#define QKV_OFF_Z3 (3 * (size_t)QKV_SZ)
#define O_OFF    9043968

// ---------------- weight transpose, LDS-tiled, coalesced both sides ----------------
__global__ __launch_bounds__(256) void transpose_w(
    const float* __restrict__ Wq, const float* __restrict__ Wq2,
    const float* __restrict__ Wk, const float* __restrict__ Wv,
    const float* __restrict__ Wo, ushort_t* __restrict__ ws)
{
    const int z = blockIdx.z;
    const float* in;
    ushort_t* outp;
    int R, C;
    float s = 1.0f;
    if (z < 4) {
        in = (z == 0) ? Wq : (z == 1) ? Wq2 : (z == 2) ? Wk : Wv;
        outp = ws + WT_OFF + (size_t)z * 131072;
        R = 512; C = 256;
        if (z < 2) s = 0.125f * LOG2E;   // fold attn scale + exp2 conversion into Wq/Wq2
    } else {
        in = Wo; outp = ws + WOT_OFF; R = 256; C = 512;
    }
    const int rt = blockIdx.x * 64, ct = blockIdx.y * 64;
    if (rt >= R || ct >= C) return;
    __shared__ float lT[64][65];
    const int tid = threadIdx.x;
    const int ci = tid & 63, ri0 = tid >> 6;
#pragma unroll
    for (int it = 0; it < 16; ++it) {
        const int r = ri0 + it * 4;
        lT[r][ci] = in[(size_t)(rt + r) * C + ct + ci];
    }
    __syncthreads();
#pragma unroll
    for (int it = 0; it < 16; ++it) {
        const int orow = ri0 + it * 4;
        outp[(size_t)(ct + orow) * R + rt + ci] = f2bf(lT[ci][orow] * s);
    }
}

// ---------------- projections: 64x256 tile per block ----------------
// z: 0: Q=x1@Wq ; 1: Q2=x2@Wq2 ; 2: K=ctx@Wk ; 3: V^T=(ctx@Wv)^T
__global__ __launch_bounds__(256) void proj_gemm(
    const float* __restrict__ x1, const float* __restrict__ x2,
    const float* __restrict__ ctx, const ushort_t* __restrict__ Wt,
    ushort_t* __restrict__ QKV)
{
    __shared__ __align__(16) ushort_t lA[64 * 40];
    __shared__ __align__(16) ushort_t lB[256 * 40];
    const int z = blockIdx.y;
    const float* A = (z == 0) ? x1 : (z == 1) ? x2 : ctx;
    const ushort_t* Bt = Wt + (size_t)z * 131072;
    const int tid = threadIdx.x;
    const int wave = tid >> 6, lane = tid & 63;
    const int quad = lane >> 4, l16 = lane & 15;
    const size_t row0 = (size_t)blockIdx.x * 64;
    const int sr = tid >> 2, sc8 = (tid & 3) << 3;

    f32x4 acc[16] = {};
    for (int k0 = 0; k0 < 512; k0 += 32) {
        const float* src = A + (row0 + sr) * 512 + k0 + sc8;
        float4 v0 = *(const float4*)src;
        float4 v1 = *(const float4*)(src + 4);
        uint4 packed;
        packed.x = pack2_rn(v0.x, v0.y);
        packed.y = pack2_rn(v0.z, v0.w);
        packed.z = pack2_rn(v1.x, v1.y);
        packed.w = pack2_rn(v1.z, v1.w);
        *(uint4*)&lA[sr * 40 + sc8] = packed;
#pragma unroll
        for (int rr = 0; rr < 4; ++rr)
            *(uint4*)&lB[(rr * 64 + sr) * 40 + sc8] =
                *(const uint4*)(Bt + (size_t)(rr * 64 + sr) * 512 + k0 + sc8);
        __syncthreads();
        bf16x8 af = *(const bf16x8*)&lA[(wave * 16 + l16) * 40 + quad * 8];
        if (z == 3) {
#pragma unroll
            for (int c = 0; c < 16; ++c) {
                bf16x8 bfr = *(const bf16x8*)&lB[(c * 16 + l16) * 40 + quad * 8];
                acc[c] = __builtin_amdgcn_mfma_f32_16x16x32_bf16(af, bfr, acc[c], 0, 0, 0);
            }
        } else {
#pragma unroll
            for (int c = 0; c < 16; ++c) {
                bf16x8 bfr = *(const bf16x8*)&lB[(c * 16 + l16) * 40 + quad * 8];
                acc[c] = __builtin_amdgcn_mfma_f32_16x16x32_bf16(bfr, af, acc[c], 0, 0, 0);
            }
        }
        __syncthreads();
    }
    if (z == 3) {
        const int b = (int)(row0 >> 11);
        const int tokl = ((int)row0 & 2047) + wave * 16 + quad * 4;
        ushort_t* Vt = QKV + QKV_OFF_Z3;
#pragma unroll
        for (int c = 0; c < 16; ++c) {
            const int col = c * 16 + l16;
            const int h = col >> 6, d = col & 63;
            uint2 w;
            w.x = pack2_rn(acc[c][0], acc[c][1]);
            w.y = pack2_rn(acc[c][2], acc[c][3]);
            *(uint2*)(Vt + ((size_t)((b * 4 + h) * 64 + d)) * 2048 + tokl) = w;
        }
    } else {
        ushort_t* C = QKV + (size_t)z * QKV_SZ;
        const size_t tok = row0 + wave * 16 + l16;
#pragma unroll
        for (int c = 0; c < 16; ++c) {
            uint2 w;
            w.x = pack2_rn(acc[c][0], acc[c][1]);
            w.y = pack2_rn(acc[c][2], acc[c][3]);
            *(uint2*)(C + tok * 256 + c * 16 + quad * 4) = w;
        }
    }
}

// ---------------- output projection: 64x256 tile, C^T orientation ----------------
__global__ __launch_bounds__(256) void out_gemm(
    const ushort_t* __restrict__ Op, const ushort_t* __restrict__ Wot,
    const float* __restrict__ bias, float* __restrict__ out)
{
    __shared__ __align__(16) ushort_t lA[64 * 40];
    __shared__ __align__(16) ushort_t lB[256 * 40];
    const int tid = threadIdx.x;
    const int wave = tid >> 6, lane = tid & 63;
    const int quad = lane >> 4, l16 = lane & 15;
    const size_t row0 = (size_t)blockIdx.x * 64;
    const int col0 = blockIdx.y * 256;
    const int sr = tid >> 2, sc8 = (tid & 3) << 3;

    f32x4 acc[16] = {};
    for (int k0 = 0; k0 < 256; k0 += 32) {
        *(uint4*)&lA[sr * 40 + sc8] = *(const uint4*)(Op + (row0 + sr) * 256 + k0 + sc8);
#pragma unroll
        for (int rr = 0; rr < 4; ++rr)
            *(uint4*)&lB[(rr * 64 + sr) * 40 + sc8] =
                *(const uint4*)(Wot + (size_t)(col0 + rr * 64 + sr) * 256 + k0 + sc8);
        __syncthreads();
        bf16x8 af = *(const bf16x8*)&lA[(wave * 16 + l16) * 40 + quad * 8];
#pragma unroll
        for (int c = 0; c < 16; ++c) {
            bf16x8 bfr = *(const bf16x8*)&lB[(c * 16 + l16) * 40 + quad * 8];
            acc[c] = __builtin_amdgcn_mfma_f32_16x16x32_bf16(bfr, af, acc[c], 0, 0, 0);
        }
        __syncthreads();
    }
    const size_t tok = row0 + wave * 16 + l16;
#pragma unroll
    for (int c = 0; c < 16; ++c) {
        const int col = col0 + c * 16 + quad * 4;
        const float4 bv = *(const float4*)&bias[col];
        float4 o;
        o.x = acc[c][0] + bv.x; o.y = acc[c][1] + bv.y;
        o.z = acc[c][2] + bv.z; o.w = acc[c][3] + bv.w;
        *(float4*)&out[tok * 512 + col] = o;
    }
}

// ---------------- fused dual-softmax flash attention, 40 KB LDS ----------------
// S^T = K·Q^T, static-max (p = exp2(s)), O^T = V^T·P^T.
// K LDS: [ktok][64 d], 16B groups XOR-swizzled by ktok&7. V^T LDS: [d][64 tok], same.
// P LDS: ONE per-wave [16 q][64 k] buffer, 8-short groups XOR-swizzled by q&7,
// reused sequentially for map1 then map2 (same-wave DS ordering makes WAR safe).
// NOTE: no min-waves launch_bounds arg — R8 showed (256,4) forces VGPR=64 and
// spills the accumulators to scratch (WRITE_SIZE 4MB -> 298MB, attn 61->127us).

#define ATTN_STAGE(MB, BUF) do {                                                        \
    _Pragma("unroll")                                                                   \
    for (int it_ = 0; it_ < 2; ++it_) {                                                 \
        const int cc_ = tid + it_ * 256;                                                \
        const int g_ = (cc_ ^ (cc_ >> 3)) & 7;                                          \
        const ushort_t* kp_ = Kb + (size_t)(tok0 + (MB) + (cc_ >> 3)) * 256 + in0 + g_ * 8; \
        __builtin_amdgcn_global_load_lds(                                               \
            (const __attribute__((address_space(1))) void*)kp_,                         \
            (__attribute__((address_space(3))) void*)&lK[BUF][cc_ * 8], 16, 0, 0);      \
        const ushort_t* vp_ = Vt + (size_t)(bh64 + (cc_ >> 3)) * 2048 + (MB) + g_ * 8;  \
        __builtin_amdgcn_global_load_lds(                                               \
            (const __attribute__((address_space(1))) void*)vp_,                         \
            (__attribute__((address_space(3))) void*)&lV[BUF][cc_ * 8], 16, 0, 0);      \
    }                                                                                   \
} while (0)

#define P_WRITE(ST, LS) do {                                                            \
    _Pragma("unroll")                                                                   \
    for (int c = 0; c < 4; ++c) {                                                       \
        float p0 = __builtin_amdgcn_exp2f(ST[c][0]);                                    \
        float p1 = __builtin_amdgcn_exp2f(ST[c][1]);                                    \
        float p2 = __builtin_amdgcn_exp2f(ST[c][2]);                                    \
        float p3 = __builtin_amdgcn_exp2f(ST[c][3]);                                    \
        LS += (p0 + p1) + (p2 + p3);                                                    \
        uint2 w; w.x = pack2_rn(p0, p1); w.y = pack2_rn(p2, p3);                        \
        *(uint2*)&lPw[l16 * 64 + ((((c * 2 + (quad >> 1)) ^ l7) & 7) << 3) +            \
                      ((quad & 1) << 2)] = w;                                           \
    }                                                                                   \
} while (0)

#define PV_MFMA(OA, PAV, P) do {                                                        \
    _Pragma("unroll")                                                                   \
    for (int c = 0; c < 4; ++c) {                                                       \
        _Pragma("unroll")                                                               \
        for (int ks = 0; ks < 2; ++ks) {                                                \
            bf16x8 vf = *(const bf16x8*)&lV[P][(c * 16 + l16) * 64 +                    \
                                              ((((ks * 4 + quad) ^ l7) & 7) << 3)];     \
            OA[c] = __builtin_amdgcn_mfma_f32_16x16x32_bf16(vf, PAV[ks], OA[c], 0, 0, 0); \
        } }                                                                             \
} while (0)

#define ATTN_ITER(I, P) do {                                                            \
    __syncthreads();                                                                    \
    { const int mn_ = ((I) + 1) * 64; if (mn_ < 2048) ATTN_STAGE(mn_, 1 - (P)); }       \
    f32x4 st1[4] = {}, st2[4] = {};                                                     \
    _Pragma("unroll")                                                                   \
    for (int c = 0; c < 4; ++c) {                                                       \
        _Pragma("unroll")                                                               \
        for (int ks = 0; ks < 2; ++ks) {                                                \
            bf16x8 kf = *(const bf16x8*)&lK[P][(c * 16 + l16) * 64 +                    \
                                              ((((ks * 4 + quad) ^ l7) & 7) << 3)];     \
            st1[c] = __builtin_amdgcn_mfma_f32_16x16x32_bf16(kf, q1f[ks], st1[c], 0, 0, 0); \
            st2[c] = __builtin_amdgcn_mfma_f32_16x16x32_bf16(kf, q2f[ks], st2[c], 0, 0, 0); \
        } }                                                                             \
    P_WRITE(st1, l1);                                                                   \
    bf16x8 pa[2];                                                                       \
    _Pragma("unroll")                                                                   \
    for (int ks = 0; ks < 2; ++ks)                                                      \
        pa[ks] = *(const bf16x8*)&lPw[l16 * 64 + ((((ks * 4 + quad) ^ l7) & 7) << 3)];  \
    PV_MFMA(o1, pa, P);                                                                 \
    P_WRITE(st2, l2);                                                                   \
    _Pragma("unroll")                                                                   \
    for (int ks = 0; ks < 2; ++ks)                                                      \
        pa[ks] = *(const bf16x8*)&lPw[l16 * 64 + ((((ks * 4 + quad) ^ l7) & 7) << 3)];  \
    PV_MFMA(o2, pa, P);                                                                 \
} while (0)

__global__ __launch_bounds__(256) void attn_fused(
    const ushort_t* __restrict__ Qb, const ushort_t* __restrict__ Q2b,
    const ushort_t* __restrict__ Kb, const ushort_t* __restrict__ Vt,
    ushort_t* __restrict__ Ob)
{
    __shared__ __align__(16) ushort_t lK[2][64 * 64];   // 16 KB
    __shared__ __align__(16) ushort_t lV[2][64 * 64];   // 16 KB
    __shared__ __align__(16) ushort_t lP[4][16 * 64];   // 8 KB  -> 40 KB total

    const int qt = blockIdx.x;
    const int bh = blockIdx.y;
    const int tid = threadIdx.x;
    const int wave = tid >> 6, lane = tid & 63;
    const int quad = lane >> 4, l16 = lane & 15;
    const int l7 = l16 & 7;
    const size_t tok0 = (size_t)(bh >> 2) * 2048;
    const int in0 = (bh & 3) * 64;
    const int bh64 = bh * 64;
    ushort_t* lPw = &lP[wave][0];

    // Q fragments: direct global load (B-operand layout is row-contiguous 16B)
    bf16x8 q1f[2], q2f[2];
    {
        const ushort_t* qr1 = Qb  + (tok0 + qt * 64 + wave * 16 + l16) * 256 + in0;
        const ushort_t* qr2 = Q2b + (tok0 + qt * 64 + wave * 16 + l16) * 256 + in0;
#pragma unroll
        for (int ks = 0; ks < 2; ++ks) {
            q1f[ks] = *(const bf16x8*)(qr1 + ks * 32 + quad * 8);
            q2f[ks] = *(const bf16x8*)(qr2 + ks * 32 + quad * 8);
        }
    }

    ATTN_STAGE(0, 0);

    f32x4 o1[4] = {}, o2[4] = {};
    float l1 = 0.f, l2 = 0.f;

    for (int i = 0; i < 32; i += 2) {
        ATTN_ITER(i, 0);
        ATTN_ITER(i + 1, 1);
    }

    l1 += __shfl_xor(l1, 16, 64); l1 += __shfl_xor(l1, 32, 64);
    l2 += __shfl_xor(l2, 16, 64); l2 += __shfl_xor(l2, 32, 64);
    const float inv1 = 0.3f / l1, inv2 = 0.7f / l2;

    // O^T C-layout: row d = c*16 + quad*4 + r, col q = l16
    ushort_t* orow = Ob + (tok0 + qt * 64 + wave * 16 + l16) * 256 + in0;
#pragma unroll
    for (int c = 0; c < 4; ++c) {
        const float f0 = o1[c][0] * inv1 + o2[c][0] * inv2;
        const float f1 = o1[c][1] * inv1 + o2[c][1] * inv2;
        const float f2 = o1[c][2] * inv1 + o2[c][2] * inv2;
        const float f3 = o1[c][3] * inv1 + o2[c][3] * inv2;
        uint2 w; w.x = pack2_rn(f0, f1); w.y = pack2_rn(f2, f3);
        *(uint2*)(orow + c * 16 + quad * 4) = w;
    }
}

// ---------------- launch ----------------
extern "C" void kernel_launch(void* const* d_in, const int* in_sizes, int n_in,
                              void* d_out, int out_size, void* d_ws, size_t ws_size,
                              hipStream_t stream)
{
    (void)in_sizes; (void)n_in; (void)out_size; (void)ws_size;
    const float* x1  = (const float*)d_in[0];
    const float* x2  = (const float*)d_in[1];
    const float* ctx = (const float*)d_in[2];
    const float* Wq  = (const float*)d_in[3];
    const float* Wq2 = (const float*)d_in[4];
    const float* Wk  = (const float*)d_in[5];
    const float* Wv  = (const float*)d_in[6];
    const float* Wo  = (const float*)d_in[7];
    const float* bo  = (const float*)d_in[8];
    ushort_t* ws  = (ushort_t*)d_ws;
    float* out = (float*)d_out;

    ushort_t* Wt  = ws + WT_OFF;
    ushort_t* Wot = ws + WOT_OFF;
    ushort_t* QKV = ws + QKV_OFF;
    ushort_t* Q   = QKV;
    ushort_t* Q2  = QKV + 1 * (size_t)QKV_SZ;
    ushort_t* Kp  = QKV + 2 * (size_t)QKV_SZ;
    ushort_t* Vt  = QKV + 3 * (size_t)QKV_SZ;
    ushort_t* Op  = ws + O_OFF;

    transpose_w<<<dim3(8, 8, 5), 256, 0, stream>>>(Wq, Wq2, Wk, Wv, Wo, ws);
    proj_gemm  <<<dim3(128, 4), 256, 0, stream>>>(x1, x2, ctx, Wt, QKV);
    attn_fused <<<dim3(32, 16), 256, 0, stream>>>(Q, Q2, Kp, Vt, Op);
    out_gemm   <<<dim3(128, 2), 256, 0, stream>>>(Op, Wot, bo, out);
}